// Round 8
// baseline (367.404 us; speedup 1.0000x reference)
//
#include <hip/hip_runtime.h>
#include <hip/hip_bf16.h>
#include <cstdint>

#define BB   4
#define SENC 2048
#define SDEC 1024
#define DM   1024
#define NH   16
#define HD   64

using short8 = __attribute__((ext_vector_type(8))) short;
using f32x4  = __attribute__((ext_vector_type(4))) float;

// round-half-up fp32 -> bf16 (2 VALU ops)
__device__ inline unsigned short f2bf(float f) {
    return (unsigned short)((__builtin_bit_cast(unsigned int, f) + 0x8000u) >> 16);
}
// pack two fp32 -> bf16x2 dword
__device__ inline unsigned int pk2bf(float a, float b) {
    return ((__builtin_bit_cast(unsigned int, a) + 0x8000u) >> 16) |
           ((__builtin_bit_cast(unsigned int, b) + 0x8000u) & 0xffff0000u);
}

__device__ inline float fexp2(float x) {
#if __has_builtin(__builtin_amdgcn_exp2f)
    return __builtin_amdgcn_exp2f(x);
#else
    return exp2f(x);
#endif
}

// ---------------- prep: activations -> A-frag-major bf16; weights -> B-frag-major; mask -> float ----
__global__ __launch_bounds__(256) void prep_kernel(
    const float* __restrict__ dec, const float* __restrict__ enc,
    unsigned short* __restrict__ decb, unsigned short* __restrict__ encb,
    const float* __restrict__ qw, const float* __restrict__ kw,
    const float* __restrict__ vw, const float* __restrict__ ow,
    unsigned short* __restrict__ qwt, unsigned short* __restrict__ kvwt,
    unsigned short* __restrict__ owt,
    const int* __restrict__ mask, float* __restrict__ maskf) {
    const int id = blockIdx.x, tid = threadIdx.x;
    if (id < 3072) {
        __shared__ unsigned short t[64][72];
        const int rt = id >> 4, ct = id & 15, k0 = ct * 64;
        const float* src; unsigned short* dst; int m0;
        if (rt < 64) { src = dec; dst = decb; m0 = rt * 64; }
        else         { src = enc; dst = encb; m0 = (rt - 64) * 64; }
        #pragma unroll
        for (int i = 0; i < 4; ++i) {
            const int row = i * 16 + (tid >> 4), col4 = (tid & 15) * 4;
            float4 v = *(const float4*)&src[(size_t)(m0 + row) * DM + k0 + col4];
            ushort4 o;
            o.x = f2bf(v.x); o.y = f2bf(v.y); o.z = f2bf(v.z); o.w = f2bf(v.w);
            *(ushort4*)&t[row][col4] = o;
        }
        __syncthreads();
        const int f = tid >> 3, sub = tid & 7;
        const int mt = f >> 3, kc = f & 7;
        const int row0 = mt * 16 + sub * 2;
        short8 a = *(const short8*)&t[row0][kc * 8];
        short8 b = *(const short8*)&t[row0 + 1][kc * 8];
        size_t off = (size_t)(m0 / 16 + mt) * 16384 + (size_t)(k0 / 8 + kc) * 128 + sub * 16;
        *(short8*)&dst[off] = a;
        *(short8*)&dst[off + 8] = b;
        return;
    }
    if (id == 4096) {
        for (int j = tid; j < BB * SENC; j += 256) maskf[j] = mask[j] ? -1e30f : 0.0f;
        return;
    }
    __shared__ float t[64][65];
    const int id2 = id - 3072;
    const int z = id2 >> 8, ky = (id2 >> 4) & 15, nx = id2 & 15;
    const float* src; unsigned short* dst;
    switch (z) {
        case 0:  src = qw; dst = qwt; break;
        case 1:  src = kw; dst = kvwt; break;
        case 2:  src = vw; dst = kvwt + (size_t)64 * 16384; break;
        default: src = ow; dst = owt; break;
    }
    const int k0 = ky * 64, n0 = nx * 64;
    #pragma unroll
    for (int it = 0; it < 16; ++it) {
        int e = it * 256 + tid, r = e >> 6, c = e & 63;
        t[r][c] = src[(size_t)(k0 + r) * DM + n0 + c];
    }
    __syncthreads();
    #pragma unroll
    for (int it = 0; it < 16; ++it) {
        int e = it * 256 + tid, r = e >> 6, c = e & 63;
        size_t off = (size_t)((n0 + r) >> 4) * 16384 + (size_t)((k0 + c) >> 3) * 128
                   + ((r & 15) << 3) + (c & 7);
        dst[off] = f2bf(t[c][r]);
    }
}

// ---------------- fused Q/K/V projection GEMM: zero-LDS, barrier-free ----------------
__global__ __launch_bounds__(256) void gemm_qkv_kernel(
    const unsigned short* __restrict__ encb, const unsigned short* __restrict__ decb,
    const unsigned short* __restrict__ kvwt, const unsigned short* __restrict__ qwt,
    const float* __restrict__ q_b, const float* __restrict__ k_b, const float* __restrict__ v_b,
    unsigned short* __restrict__ Qb, unsigned short* __restrict__ Kb,
    unsigned short* __restrict__ Vtb) {
    const int id = blockIdx.x;
    const bool isKV = id < 1024;
    const unsigned short *A, *Bw;
    int m0, n0;
    if (isKV) {
        const int x = id & 7, w = id >> 3;
        A = encb; Bw = kvwt;
        m0 = (x * 8 + (w >> 4)) * 128;
        n0 = (w & 15) * 128;
    } else {
        const int i2 = id - 1024, x = i2 & 7, w = i2 >> 3;
        A = decb; Bw = qwt;
        m0 = (x * 4 + (w >> 3)) * 128;
        n0 = (w & 7) * 128;
    }
    const int tid = threadIdx.x;
    const int wave = tid >> 6, lane = tid & 63, quad = lane >> 4, l16 = lane & 15;
    const int wr = wave >> 1, wc = wave & 1;
    const int lo = quad * 128 + l16 * 8;
    const unsigned short* Ap = A + (size_t)(m0 / 16 + wr * 4) * 16384 + lo;
    const unsigned short* Bp = Bw + (size_t)(n0 / 16 + wc * 4) * 16384 + lo;
    f32x4 acc[4][4] = {};
    short8 ac[4], bc[4], an[4], bn[4];
    #pragma unroll
    for (int i = 0; i < 4; ++i) {
        ac[i] = *(const short8*)&Ap[i * 16384];
        bc[i] = *(const short8*)&Bp[i * 16384];
    }
    #pragma unroll 2
    for (int it = 0; it < 32; ++it) {
        if (it < 31) {
            const int ko = (it + 1) * 512;
            #pragma unroll
            for (int i = 0; i < 4; ++i) {
                an[i] = *(const short8*)&Ap[i * 16384 + ko];
                bn[i] = *(const short8*)&Bp[i * 16384 + ko];
            }
        }
        #pragma unroll
        for (int i = 0; i < 4; ++i)
            #pragma unroll
            for (int j = 0; j < 4; ++j)
                acc[i][j] = __builtin_amdgcn_mfma_f32_16x16x32_bf16(ac[i], bc[j], acc[i][j], 0, 0, 0);
        #pragma unroll
        for (int i = 0; i < 4; ++i) { ac[i] = an[i]; bc[i] = bn[i]; }
    }
    #pragma unroll
    for (int i = 0; i < 4; ++i) {
        #pragma unroll
        for (int j = 0; j < 4; ++j) {
            const int gc = n0 + wc * 64 + j * 16 + l16;
            const int gr0 = m0 + wr * 64 + i * 16 + quad * 4;
            if (!isKV) {
                const float bv = q_b[gc];
                const int h = gc >> 6, d = gc & 63;
                #pragma unroll
                for (int rr = 0; rr < 4; ++rr) {
                    int gr = gr0 + rr, b = gr >> 10, sq = gr & 1023;
                    float v = (acc[i][j][rr] + bv) * 0.18033688011112042f;  // 1/(8 ln2)
                    Qb[(((size_t)(b * NH + h) * SDEC + sq) << 6) + d] = f2bf(v);
                }
            } else if (gc < 1024) {
                const float bv = k_b[gc];
                const int h = gc >> 6, d = gc & 63;
                #pragma unroll
                for (int rr = 0; rr < 4; ++rr) {
                    int gr = gr0 + rr, b = gr >> 11, sk = gr & 2047;
                    size_t off = (size_t)(b * NH + h) * 131072 + (size_t)(sk >> 4) * 1024
                               + ((d >> 3) << 7) + ((sk & 15) << 3) + (d & 7);
                    Kb[off] = f2bf(acc[i][j][rr] + bv);
                }
            } else {
                const int gc2 = gc & 1023;
                const float bv = v_b[gc2];
                const int h = gc2 >> 6, d = gc2 & 63;
                const int b = gr0 >> 11, sk0 = gr0 & 2047;
                size_t off = (size_t)(b * NH + h) * 131072 + (size_t)(d >> 4) * 32768
                           + (size_t)(sk0 >> 3) * 128 + ((d & 15) << 3) + (sk0 & 7);
                uint2 pk;
                pk.x = pk2bf(acc[i][j][0] + bv, acc[i][j][1] + bv);
                pk.y = pk2bf(acc[i][j][2] + bv, acc[i][j][3] + bv);
                *(uint2*)&Vtb[off] = pk;
            }
        }
    }
}

// ---------------- output projection: zero-LDS, 64x128 tile, XCD swizzle ------------
__global__ __launch_bounds__(256) void gemm_o_kernel(const unsigned short* __restrict__ A,
                                                     const unsigned short* __restrict__ Bw,
                                                     const float* __restrict__ bias,
                                                     float* __restrict__ Cout) {
    const int id = blockIdx.x, x = id & 7, w = id >> 3;
    const int m0 = (x * 8 + (w >> 3)) * 64, n0 = (w & 7) * 128;
    const int tid = threadIdx.x;
    const int wave = tid >> 6, lane = tid & 63, quad = lane >> 4, l16 = lane & 15;
    const int lo = quad * 128 + l16 * 8;
    const unsigned short* Ap = A + (size_t)(m0 / 16) * 16384 + lo;
    const unsigned short* Bp = Bw + (size_t)(n0 / 16 + wave * 2) * 16384 + lo;
    f32x4 acc[4][2] = {};
    short8 ac[4], bc[2], an[4], bn[2];
    #pragma unroll
    for (int i = 0; i < 4; ++i) ac[i] = *(const short8*)&Ap[i * 16384];
    #pragma unroll
    for (int j = 0; j < 2; ++j) bc[j] = *(const short8*)&Bp[j * 16384];
    #pragma unroll 2
    for (int it = 0; it < 32; ++it) {
        if (it < 31) {
            const int ko = (it + 1) * 512;
            #pragma unroll
            for (int i = 0; i < 4; ++i) an[i] = *(const short8*)&Ap[i * 16384 + ko];
            #pragma unroll
            for (int j = 0; j < 2; ++j) bn[j] = *(const short8*)&Bp[j * 16384 + ko];
        }
        #pragma unroll
        for (int i = 0; i < 4; ++i)
            #pragma unroll
            for (int j = 0; j < 2; ++j)
                acc[i][j] = __builtin_amdgcn_mfma_f32_16x16x32_bf16(ac[i], bc[j], acc[i][j], 0, 0, 0);
        #pragma unroll
        for (int i = 0; i < 4; ++i) ac[i] = an[i];
        #pragma unroll
        for (int j = 0; j < 2; ++j) bc[j] = bn[j];
    }
    #pragma unroll
    for (int i = 0; i < 4; ++i)
        #pragma unroll
        for (int j = 0; j < 2; ++j) {
            const int gc = n0 + wave * 32 + j * 16 + l16;
            const float bv = bias[gc];
            #pragma unroll
            for (int rr = 0; rr < 4; ++rr) {
                const int gr = m0 + i * 16 + quad * 4 + rr;
                Cout[(size_t)gr * DM + gc] = acc[i][j][rr] + bv;
            }
        }
}

// ---------------- flash cross-attention: key-split, 256 threads, NO launch_bounds ------------
// 4 waves = 2 q-waves (32 queries each) x 2 key-halves (1024 keys, 16 iters each).
// Fixed-base softmax => partials combine by addition: ks=1 dumps (o,lsum) to LDS, one barrier,
// ks=0 adds+normalizes+stores A-frag-major. Grid 1024 (~4 blocks/CU = 16 waves/CU).
// R7 lesson: launch_bounds(512,4) forced 64 VGPR -> 413MB spill traffic; natural alloc ~96-110.
__global__ void attn_kernel(const unsigned short* __restrict__ Qb,
                            const unsigned short* __restrict__ Kb,
                            const unsigned short* __restrict__ Vtb,
                            const float* __restrict__ maskf,
                            unsigned short* __restrict__ Xb) {
    __shared__ __align__(16) unsigned short Ps[4][16 * 72];  // 9.2 KB
    __shared__ __align__(16) float Sm[2][2176];              // 17.4 KB partial o + lsum
    const int id = blockIdx.x, x = id & 7, r = id >> 3;
    const int bh = x * 8 + (r & 7), qt = r >> 3;             // 64 bh x 16 q-tiles of 64
    const int b = bh >> 4, h = bh & 15;
    const int q0 = qt * 64;
    const int tid = threadIdx.x, wave = tid >> 6, lane = tid & 63;
    const int qw = wave & 1, ks = wave >> 1;
    const int quad = lane >> 4, l16 = lane & 15;
    const int lo = quad * 128 + l16 * 8;

    const unsigned short* Kfp = Kb + (size_t)bh * 131072 + (size_t)ks * 65536 + lo;
    const unsigned short* Vfp = Vtb + (size_t)bh * 131072 + (size_t)ks * 16384 + lo;
    const float* mp = maskf + (size_t)b * SENC + ks * 1024;

    short8 qf[2][2];
    {
        const unsigned short* Qp = Qb + ((size_t)bh * SDEC + q0 + qw * 32) * HD;
        #pragma unroll
        for (int g = 0; g < 2; ++g) {
            qf[g][0] = *(const short8*)&Qp[(g * 16 + l16) * HD + quad * 8];
            qf[g][1] = *(const short8*)&Qp[(g * 16 + l16) * HD + 32 + quad * 8];
        }
    }

    float lsum[2] = {0.f, 0.f};
    f32x4 o[2][4] = {};

    #pragma unroll 2
    for (int it = 0; it < 16; ++it) {
        const int kb = it * 64;
        short8 kc0[4], kc1[4];
        const unsigned short* kt = Kfp + (size_t)(kb >> 4) * 1024;
        #pragma unroll
        for (int j = 0; j < 4; ++j) {
            kc0[j] = *(const short8*)&kt[j * 1024];
            kc1[j] = *(const short8*)&kt[j * 1024 + 512];
        }
        float4 mf[4];
        #pragma unroll
        for (int j = 0; j < 4; ++j) mf[j] = *(const float4*)&mp[kb + j * 16 + quad * 4];
        short8 vB0[4], vB1[4];
        const unsigned short* vt = Vfp + (size_t)(kb >> 3) * 128;
        #pragma unroll
        for (int j = 0; j < 4; ++j) {
            vB0[j] = *(const short8*)&vt[j * 32768];
            vB1[j] = *(const short8*)&vt[j * 32768 + 512];
        }
        #pragma unroll
        for (int g = 0; g < 2; ++g) {
            f32x4 st[4];
            #pragma unroll
            for (int j = 0; j < 4; ++j) {
                f32x4 z = {0.f, 0.f, 0.f, 0.f};
                z = __builtin_amdgcn_mfma_f32_16x16x32_bf16(kc0[j], qf[g][0], z, 0, 0, 0);
                st[j] = __builtin_amdgcn_mfma_f32_16x16x32_bf16(kc1[j], qf[g][1], z, 0, 0, 0);
            }
            #pragma unroll
            for (int j = 0; j < 4; ++j) {
                float p0 = fexp2(st[j][0] + mf[j].x);
                float p1 = fexp2(st[j][1] + mf[j].y);
                float p2 = fexp2(st[j][2] + mf[j].z);
                float p3 = fexp2(st[j][3] + mf[j].w);
                lsum[g] += (p0 + p1) + (p2 + p3);
                uint2 pkv;
                pkv.x = pk2bf(p0, p1);
                pkv.y = pk2bf(p2, p3);
                *(uint2*)&Ps[wave][l16 * 72 + j * 16 + quad * 4] = pkv;
            }
            asm volatile("s_waitcnt lgkmcnt(0)" ::: "memory");  // Ps write->read, same wave
            short8 pA0 = *(const short8*)&Ps[wave][l16 * 72 + quad * 8];
            short8 pA1 = *(const short8*)&Ps[wave][l16 * 72 + 32 + quad * 8];
            #pragma unroll
            for (int dj = 0; dj < 4; ++dj) {
                o[g][dj] = __builtin_amdgcn_mfma_f32_16x16x32_bf16(pA0, vB0[dj], o[g][dj], 0, 0, 0);
                o[g][dj] = __builtin_amdgcn_mfma_f32_16x16x32_bf16(pA1, vB1[dj], o[g][dj], 0, 0, 0);
            }
        }
    }

    if (ks == 1) {  // dump partial (o, lsum) for the partner q-wave
        float* dst = Sm[qw];
        #pragma unroll
        for (int g = 0; g < 2; ++g)
            #pragma unroll
            for (int dj = 0; dj < 4; ++dj)
                *(f32x4*)&dst[lane * 32 + g * 16 + dj * 4] = o[g][dj];
        dst[2048 + lane] = lsum[0];
        dst[2112 + lane] = lsum[1];
    }
    __syncthreads();
    if (ks == 0) {
        const float* src = Sm[qw];
        #pragma unroll
        for (int g = 0; g < 2; ++g) {
            #pragma unroll
            for (int dj = 0; dj < 4; ++dj) {
                f32x4 p = *(const f32x4*)&src[lane * 32 + g * 16 + dj * 4];
                o[g][dj] += p;
            }
            lsum[g] += src[2048 + g * 64 + lane];
            float lg = lsum[g];
            lg += __shfl_xor(lg, 16);
            lg += __shfl_xor(lg, 32);
            const int mtile = (b * 1024 + q0 + qw * 32 + g * 16) >> 4;
            const int kbase = h * 64;
            #pragma unroll
            for (int rr = 0; rr < 4; ++rr) {
                float iv = 1.0f / __shfl(lg, quad * 4 + rr, 64);
                #pragma unroll
                for (int dj = 0; dj < 4; ++dj) {
                    const int k = kbase + dj * 16 + l16;
                    size_t off = (size_t)mtile * 16384 + (size_t)(k >> 3) * 128
                               + ((quad * 4 + rr) << 3) + (k & 7);
                    Xb[off] = f2bf(o[g][dj][rr] * iv);
                }
            }
        }
    }
}

extern "C" void kernel_launch(void* const* d_in, const int* in_sizes, int n_in,
                              void* d_out, int out_size, void* d_ws, size_t ws_size,
                              hipStream_t stream) {
    const float* enc   = (const float*)d_in[0];
    const int*   emask = (const int*)d_in[1];
    const float* dec   = (const float*)d_in[2];
    const float* q_w   = (const float*)d_in[3];
    const float* q_b   = (const float*)d_in[4];
    const float* k_w   = (const float*)d_in[5];
    const float* k_b   = (const float*)d_in[6];
    const float* v_w   = (const float*)d_in[7];
    const float* v_b   = (const float*)d_in[8];
    const float* o_w   = (const float*)d_in[9];
    const float* o_b   = (const float*)d_in[10];
    float* out = (float*)d_out;

    char* ws = (char*)d_ws;
    unsigned short* decb = (unsigned short*)ws; ws += (size_t)4096 * 1024 * 2;
    unsigned short* encb = (unsigned short*)ws; ws += (size_t)8192 * 1024 * 2;
    unsigned short* qwt  = (unsigned short*)ws; ws += (size_t)1024 * 1024 * 2;
    unsigned short* kvwt = (unsigned short*)ws; ws += (size_t)2048 * 1024 * 2;
    unsigned short* owt  = (unsigned short*)ws; ws += (size_t)1024 * 1024 * 2;
    unsigned short* Qb   = (unsigned short*)ws; ws += (size_t)BB * NH * SDEC * HD * 2;
    unsigned short* Kb   = (unsigned short*)ws; ws += (size_t)BB * NH * SENC * HD * 2;
    unsigned short* Vtb  = (unsigned short*)ws; ws += (size_t)BB * NH * HD * SENC * 2;
    unsigned short* Xb   = (unsigned short*)ws; ws += (size_t)4096 * 1024 * 2;
    float*          mkf  = (float*)ws;          ws += (size_t)BB * SENC * 4;

    prep_kernel<<<4097, 256, 0, stream>>>(dec, enc, decb, encb, q_w, k_w, v_w, o_w,
                                          qwt, kvwt, owt, emask, mkf);
    gemm_qkv_kernel<<<1280, 256, 0, stream>>>(encb, decb, kvwt, qwt, q_b, k_b, v_b, Qb, Kb, Vtb);
    attn_kernel<<<1024, 256, 0, stream>>>(Qb, Kb, Vtb, mkf, Xb);
    gemm_o_kernel<<<512, 256, 0, stream>>>(Xb, owt, o_b, out);
}

// Round 9
// 256.932 us; speedup vs baseline: 1.4300x; 1.4300x over previous
//
#include <hip/hip_runtime.h>
#include <hip/hip_bf16.h>
#include <cstdint>

#define BB   4
#define SENC 2048
#define SDEC 1024
#define DM   1024
#define NH   16
#define HD   64

using short8 = __attribute__((ext_vector_type(8))) short;
using f32x4  = __attribute__((ext_vector_type(4))) float;

// round-half-up fp32 -> bf16 (2 VALU ops)
__device__ inline unsigned short f2bf(float f) {
    return (unsigned short)((__builtin_bit_cast(unsigned int, f) + 0x8000u) >> 16);
}
// pack two fp32 -> bf16x2 dword
__device__ inline unsigned int pk2bf(float a, float b) {
    return ((__builtin_bit_cast(unsigned int, a) + 0x8000u) >> 16) |
           ((__builtin_bit_cast(unsigned int, b) + 0x8000u) & 0xffff0000u);
}

__device__ inline float fexp2(float x) {
#if __has_builtin(__builtin_amdgcn_exp2f)
    return __builtin_amdgcn_exp2f(x);
#else
    return exp2f(x);
#endif
}

// ---------------- prep: activations -> A-frag-major bf16; weights -> B-frag-major; mask -> float ----
__global__ __launch_bounds__(256) void prep_kernel(
    const float* __restrict__ dec, const float* __restrict__ enc,
    unsigned short* __restrict__ decb, unsigned short* __restrict__ encb,
    const float* __restrict__ qw, const float* __restrict__ kw,
    const float* __restrict__ vw, const float* __restrict__ ow,
    unsigned short* __restrict__ qwt, unsigned short* __restrict__ kvwt,
    unsigned short* __restrict__ owt,
    const int* __restrict__ mask, float* __restrict__ maskf) {
    const int id = blockIdx.x, tid = threadIdx.x;
    if (id < 3072) {
        __shared__ unsigned short t[64][72];
        const int rt = id >> 4, ct = id & 15, k0 = ct * 64;
        const float* src; unsigned short* dst; int m0;
        if (rt < 64) { src = dec; dst = decb; m0 = rt * 64; }
        else         { src = enc; dst = encb; m0 = (rt - 64) * 64; }
        #pragma unroll
        for (int i = 0; i < 4; ++i) {
            const int row = i * 16 + (tid >> 4), col4 = (tid & 15) * 4;
            float4 v = *(const float4*)&src[(size_t)(m0 + row) * DM + k0 + col4];
            ushort4 o;
            o.x = f2bf(v.x); o.y = f2bf(v.y); o.z = f2bf(v.z); o.w = f2bf(v.w);
            *(ushort4*)&t[row][col4] = o;
        }
        __syncthreads();
        const int f = tid >> 3, sub = tid & 7;
        const int mt = f >> 3, kc = f & 7;
        const int row0 = mt * 16 + sub * 2;
        short8 a = *(const short8*)&t[row0][kc * 8];
        short8 b = *(const short8*)&t[row0 + 1][kc * 8];
        size_t off = (size_t)(m0 / 16 + mt) * 16384 + (size_t)(k0 / 8 + kc) * 128 + sub * 16;
        *(short8*)&dst[off] = a;
        *(short8*)&dst[off + 8] = b;
        return;
    }
    if (id == 4096) {
        for (int j = tid; j < BB * SENC; j += 256) maskf[j] = mask[j] ? -1e30f : 0.0f;
        return;
    }
    __shared__ float t[64][65];
    const int id2 = id - 3072;
    const int z = id2 >> 8, ky = (id2 >> 4) & 15, nx = id2 & 15;
    const float* src; unsigned short* dst;
    switch (z) {
        case 0:  src = qw; dst = qwt; break;
        case 1:  src = kw; dst = kvwt; break;
        case 2:  src = vw; dst = kvwt + (size_t)64 * 16384; break;
        default: src = ow; dst = owt; break;
    }
    const int k0 = ky * 64, n0 = nx * 64;
    #pragma unroll
    for (int it = 0; it < 16; ++it) {
        int e = it * 256 + tid, r = e >> 6, c = e & 63;
        t[r][c] = src[(size_t)(k0 + r) * DM + n0 + c];
    }
    __syncthreads();
    #pragma unroll
    for (int it = 0; it < 16; ++it) {
        int e = it * 256 + tid, r = e >> 6, c = e & 63;
        size_t off = (size_t)((n0 + r) >> 4) * 16384 + (size_t)((k0 + c) >> 3) * 128
                   + ((r & 15) << 3) + (c & 7);
        dst[off] = f2bf(t[c][r]);
    }
}

// ---------------- fused Q/K/V projection GEMM: zero-LDS, barrier-free ----------------
__global__ __launch_bounds__(256) void gemm_qkv_kernel(
    const unsigned short* __restrict__ encb, const unsigned short* __restrict__ decb,
    const unsigned short* __restrict__ kvwt, const unsigned short* __restrict__ qwt,
    const float* __restrict__ q_b, const float* __restrict__ k_b, const float* __restrict__ v_b,
    unsigned short* __restrict__ Qb, unsigned short* __restrict__ Kb,
    unsigned short* __restrict__ Vtb) {
    const int id = blockIdx.x;
    const bool isKV = id < 1024;
    const unsigned short *A, *Bw;
    int m0, n0;
    if (isKV) {
        const int x = id & 7, w = id >> 3;
        A = encb; Bw = kvwt;
        m0 = (x * 8 + (w >> 4)) * 128;
        n0 = (w & 15) * 128;
    } else {
        const int i2 = id - 1024, x = i2 & 7, w = i2 >> 3;
        A = decb; Bw = qwt;
        m0 = (x * 4 + (w >> 3)) * 128;
        n0 = (w & 7) * 128;
    }
    const int tid = threadIdx.x;
    const int wave = tid >> 6, lane = tid & 63, quad = lane >> 4, l16 = lane & 15;
    const int wr = wave >> 1, wc = wave & 1;
    const int lo = quad * 128 + l16 * 8;
    const unsigned short* Ap = A + (size_t)(m0 / 16 + wr * 4) * 16384 + lo;
    const unsigned short* Bp = Bw + (size_t)(n0 / 16 + wc * 4) * 16384 + lo;
    f32x4 acc[4][4] = {};
    short8 ac[4], bc[4], an[4], bn[4];
    #pragma unroll
    for (int i = 0; i < 4; ++i) {
        ac[i] = *(const short8*)&Ap[i * 16384];
        bc[i] = *(const short8*)&Bp[i * 16384];
    }
    #pragma unroll 2
    for (int it = 0; it < 32; ++it) {
        if (it < 31) {
            const int ko = (it + 1) * 512;
            #pragma unroll
            for (int i = 0; i < 4; ++i) {
                an[i] = *(const short8*)&Ap[i * 16384 + ko];
                bn[i] = *(const short8*)&Bp[i * 16384 + ko];
            }
        }
        #pragma unroll
        for (int i = 0; i < 4; ++i)
            #pragma unroll
            for (int j = 0; j < 4; ++j)
                acc[i][j] = __builtin_amdgcn_mfma_f32_16x16x32_bf16(ac[i], bc[j], acc[i][j], 0, 0, 0);
        #pragma unroll
        for (int i = 0; i < 4; ++i) { ac[i] = an[i]; bc[i] = bn[i]; }
    }
    #pragma unroll
    for (int i = 0; i < 4; ++i) {
        #pragma unroll
        for (int j = 0; j < 4; ++j) {
            const int gc = n0 + wc * 64 + j * 16 + l16;
            const int gr0 = m0 + wr * 64 + i * 16 + quad * 4;
            if (!isKV) {
                const float bv = q_b[gc];
                const int h = gc >> 6, d = gc & 63;
                #pragma unroll
                for (int rr = 0; rr < 4; ++rr) {
                    int gr = gr0 + rr, b = gr >> 10, sq = gr & 1023;
                    float v = (acc[i][j][rr] + bv) * 0.18033688011112042f;  // 1/(8 ln2)
                    Qb[(((size_t)(b * NH + h) * SDEC + sq) << 6) + d] = f2bf(v);
                }
            } else if (gc < 1024) {
                const float bv = k_b[gc];
                const int h = gc >> 6, d = gc & 63;
                #pragma unroll
                for (int rr = 0; rr < 4; ++rr) {
                    int gr = gr0 + rr, b = gr >> 11, sk = gr & 2047;
                    size_t off = (size_t)(b * NH + h) * 131072 + (size_t)(sk >> 4) * 1024
                               + ((d >> 3) << 7) + ((sk & 15) << 3) + (d & 7);
                    Kb[off] = f2bf(acc[i][j][rr] + bv);
                }
            } else {
                const int gc2 = gc & 1023;
                const float bv = v_b[gc2];
                const int h = gc2 >> 6, d = gc2 & 63;
                const int b = gr0 >> 11, sk0 = gr0 & 2047;
                size_t off = (size_t)(b * NH + h) * 131072 + (size_t)(d >> 4) * 32768
                           + (size_t)(sk0 >> 3) * 128 + ((d & 15) << 3) + (sk0 & 7);
                uint2 pk;
                pk.x = pk2bf(acc[i][j][0] + bv, acc[i][j][1] + bv);
                pk.y = pk2bf(acc[i][j][2] + bv, acc[i][j][3] + bv);
                *(uint2*)&Vtb[off] = pk;
            }
        }
    }
}

// ---------------- output projection: zero-LDS, 64x128 tile, XCD swizzle ------------
__global__ __launch_bounds__(256) void gemm_o_kernel(const unsigned short* __restrict__ A,
                                                     const unsigned short* __restrict__ Bw,
                                                     const float* __restrict__ bias,
                                                     float* __restrict__ Cout) {
    const int id = blockIdx.x, x = id & 7, w = id >> 3;
    const int m0 = (x * 8 + (w >> 3)) * 64, n0 = (w & 7) * 128;
    const int tid = threadIdx.x;
    const int wave = tid >> 6, lane = tid & 63, quad = lane >> 4, l16 = lane & 15;
    const int lo = quad * 128 + l16 * 8;
    const unsigned short* Ap = A + (size_t)(m0 / 16) * 16384 + lo;
    const unsigned short* Bp = Bw + (size_t)(n0 / 16 + wave * 2) * 16384 + lo;
    f32x4 acc[4][2] = {};
    short8 ac[4], bc[2], an[4], bn[2];
    #pragma unroll
    for (int i = 0; i < 4; ++i) ac[i] = *(const short8*)&Ap[i * 16384];
    #pragma unroll
    for (int j = 0; j < 2; ++j) bc[j] = *(const short8*)&Bp[j * 16384];
    #pragma unroll 2
    for (int it = 0; it < 32; ++it) {
        if (it < 31) {
            const int ko = (it + 1) * 512;
            #pragma unroll
            for (int i = 0; i < 4; ++i) an[i] = *(const short8*)&Ap[i * 16384 + ko];
            #pragma unroll
            for (int j = 0; j < 2; ++j) bn[j] = *(const short8*)&Bp[j * 16384 + ko];
        }
        #pragma unroll
        for (int i = 0; i < 4; ++i)
            #pragma unroll
            for (int j = 0; j < 2; ++j)
                acc[i][j] = __builtin_amdgcn_mfma_f32_16x16x32_bf16(ac[i], bc[j], acc[i][j], 0, 0, 0);
        #pragma unroll
        for (int i = 0; i < 4; ++i) ac[i] = an[i];
        #pragma unroll
        for (int j = 0; j < 2; ++j) bc[j] = bn[j];
    }
    #pragma unroll
    for (int i = 0; i < 4; ++i)
        #pragma unroll
        for (int j = 0; j < 2; ++j) {
            const int gc = n0 + wave * 32 + j * 16 + l16;
            const float bv = bias[gc];
            #pragma unroll
            for (int rr = 0; rr < 4; ++rr) {
                const int gr = m0 + i * 16 + quad * 4 + rr;
                Cout[(size_t)gr * DM + gc] = acc[i][j][rr] + bv;
            }
        }
}

// ---------------- flash cross-attention: key-split, __launch_bounds__(256) ------------
// 4 waves = 2 q-waves (32 queries each) x 2 key-halves (1024 keys, 16 iters each).
// Fixed-base softmax => partials combine by addition: ks=1 dumps (o,lsum) to LDS, one barrier,
// ks=0 adds+normalizes+stores A-frag-major. Grid 1024 (~4 blocks/CU = 16 waves/CU).
// R7/R8 lesson: (512,4) forced 64 VGPR; NO bounds also defaults to 64 (1024-thread assumption).
// __launch_bounds__(256) with no min-waves arg gives natural ~96-130 VGPR, no spill (R5/R6).
__global__ __launch_bounds__(256) void attn_kernel(const unsigned short* __restrict__ Qb,
                                                   const unsigned short* __restrict__ Kb,
                                                   const unsigned short* __restrict__ Vtb,
                                                   const float* __restrict__ maskf,
                                                   unsigned short* __restrict__ Xb) {
    __shared__ __align__(16) unsigned short Ps[4][16 * 72];  // 9.2 KB
    __shared__ __align__(16) float Sm[2][2176];              // 17.4 KB partial o + lsum
    const int id = blockIdx.x, x = id & 7, r = id >> 3;
    const int bh = x * 8 + (r & 7), qt = r >> 3;             // 64 bh x 16 q-tiles of 64
    const int b = bh >> 4, h = bh & 15;
    const int q0 = qt * 64;
    const int tid = threadIdx.x, wave = tid >> 6, lane = tid & 63;
    const int qw = wave & 1, ks = wave >> 1;
    const int quad = lane >> 4, l16 = lane & 15;
    const int lo = quad * 128 + l16 * 8;

    const unsigned short* Kfp = Kb + (size_t)bh * 131072 + (size_t)ks * 65536 + lo;
    const unsigned short* Vfp = Vtb + (size_t)bh * 131072 + (size_t)ks * 16384 + lo;
    const float* mp = maskf + (size_t)b * SENC + ks * 1024;

    short8 qf[2][2];
    {
        const unsigned short* Qp = Qb + ((size_t)bh * SDEC + q0 + qw * 32) * HD;
        #pragma unroll
        for (int g = 0; g < 2; ++g) {
            qf[g][0] = *(const short8*)&Qp[(g * 16 + l16) * HD + quad * 8];
            qf[g][1] = *(const short8*)&Qp[(g * 16 + l16) * HD + 32 + quad * 8];
        }
    }

    float lsum[2] = {0.f, 0.f};
    f32x4 o[2][4] = {};

    #pragma unroll 2
    for (int it = 0; it < 16; ++it) {
        const int kb = it * 64;
        short8 kc0[4], kc1[4];
        const unsigned short* kt = Kfp + (size_t)(kb >> 4) * 1024;
        #pragma unroll
        for (int j = 0; j < 4; ++j) {
            kc0[j] = *(const short8*)&kt[j * 1024];
            kc1[j] = *(const short8*)&kt[j * 1024 + 512];
        }
        float4 mf[4];
        #pragma unroll
        for (int j = 0; j < 4; ++j) mf[j] = *(const float4*)&mp[kb + j * 16 + quad * 4];
        short8 vB0[4], vB1[4];
        const unsigned short* vt = Vfp + (size_t)(kb >> 3) * 128;
        #pragma unroll
        for (int j = 0; j < 4; ++j) {
            vB0[j] = *(const short8*)&vt[j * 32768];
            vB1[j] = *(const short8*)&vt[j * 32768 + 512];
        }
        #pragma unroll
        for (int g = 0; g < 2; ++g) {
            f32x4 st[4];
            #pragma unroll
            for (int j = 0; j < 4; ++j) {
                f32x4 z = {0.f, 0.f, 0.f, 0.f};
                z = __builtin_amdgcn_mfma_f32_16x16x32_bf16(kc0[j], qf[g][0], z, 0, 0, 0);
                st[j] = __builtin_amdgcn_mfma_f32_16x16x32_bf16(kc1[j], qf[g][1], z, 0, 0, 0);
            }
            #pragma unroll
            for (int j = 0; j < 4; ++j) {
                float p0 = fexp2(st[j][0] + mf[j].x);
                float p1 = fexp2(st[j][1] + mf[j].y);
                float p2 = fexp2(st[j][2] + mf[j].z);
                float p3 = fexp2(st[j][3] + mf[j].w);
                lsum[g] += (p0 + p1) + (p2 + p3);
                uint2 pkv;
                pkv.x = pk2bf(p0, p1);
                pkv.y = pk2bf(p2, p3);
                *(uint2*)&Ps[wave][l16 * 72 + j * 16 + quad * 4] = pkv;
            }
            asm volatile("s_waitcnt lgkmcnt(0)" ::: "memory");  // Ps write->read, same wave
            short8 pA0 = *(const short8*)&Ps[wave][l16 * 72 + quad * 8];
            short8 pA1 = *(const short8*)&Ps[wave][l16 * 72 + 32 + quad * 8];
            #pragma unroll
            for (int dj = 0; dj < 4; ++dj) {
                o[g][dj] = __builtin_amdgcn_mfma_f32_16x16x32_bf16(pA0, vB0[dj], o[g][dj], 0, 0, 0);
                o[g][dj] = __builtin_amdgcn_mfma_f32_16x16x32_bf16(pA1, vB1[dj], o[g][dj], 0, 0, 0);
            }
        }
    }

    if (ks == 1) {  // dump partial (o, lsum) for the partner q-wave
        float* dst = Sm[qw];
        #pragma unroll
        for (int g = 0; g < 2; ++g)
            #pragma unroll
            for (int dj = 0; dj < 4; ++dj)
                *(f32x4*)&dst[lane * 32 + g * 16 + dj * 4] = o[g][dj];
        dst[2048 + lane] = lsum[0];
        dst[2112 + lane] = lsum[1];
    }
    __syncthreads();
    if (ks == 0) {
        const float* src = Sm[qw];
        #pragma unroll
        for (int g = 0; g < 2; ++g) {
            #pragma unroll
            for (int dj = 0; dj < 4; ++dj) {
                f32x4 p = *(const f32x4*)&src[lane * 32 + g * 16 + dj * 4];
                o[g][dj] += p;
            }
            lsum[g] += src[2048 + g * 64 + lane];
            float lg = lsum[g];
            lg += __shfl_xor(lg, 16);
            lg += __shfl_xor(lg, 32);
            const int mtile = (b * 1024 + q0 + qw * 32 + g * 16) >> 4;
            const int kbase = h * 64;
            #pragma unroll
            for (int rr = 0; rr < 4; ++rr) {
                float iv = 1.0f / __shfl(lg, quad * 4 + rr, 64);
                #pragma unroll
                for (int dj = 0; dj < 4; ++dj) {
                    const int k = kbase + dj * 16 + l16;
                    size_t off = (size_t)mtile * 16384 + (size_t)(k >> 3) * 128
                               + ((quad * 4 + rr) << 3) + (k & 7);
                    Xb[off] = f2bf(o[g][dj][rr] * iv);
                }
            }
        }
    }
}

extern "C" void kernel_launch(void* const* d_in, const int* in_sizes, int n_in,
                              void* d_out, int out_size, void* d_ws, size_t ws_size,
                              hipStream_t stream) {
    const float* enc   = (const float*)d_in[0];
    const int*   emask = (const int*)d_in[1];
    const float* dec   = (const float*)d_in[2];
    const float* q_w   = (const float*)d_in[3];
    const float* q_b   = (const float*)d_in[4];
    const float* k_w   = (const float*)d_in[5];
    const float* k_b   = (const float*)d_in[6];
    const float* v_w   = (const float*)d_in[7];
    const float* v_b   = (const float*)d_in[8];
    const float* o_w   = (const float*)d_in[9];
    const float* o_b   = (const float*)d_in[10];
    float* out = (float*)d_out;

    char* ws = (char*)d_ws;
    unsigned short* decb = (unsigned short*)ws; ws += (size_t)4096 * 1024 * 2;
    unsigned short* encb = (unsigned short*)ws; ws += (size_t)8192 * 1024 * 2;
    unsigned short* qwt  = (unsigned short*)ws; ws += (size_t)1024 * 1024 * 2;
    unsigned short* kvwt = (unsigned short*)ws; ws += (size_t)2048 * 1024 * 2;
    unsigned short* owt  = (unsigned short*)ws; ws += (size_t)1024 * 1024 * 2;
    unsigned short* Qb   = (unsigned short*)ws; ws += (size_t)BB * NH * SDEC * HD * 2;
    unsigned short* Kb   = (unsigned short*)ws; ws += (size_t)BB * NH * SENC * HD * 2;
    unsigned short* Vtb  = (unsigned short*)ws; ws += (size_t)BB * NH * HD * SENC * 2;
    unsigned short* Xb   = (unsigned short*)ws; ws += (size_t)4096 * 1024 * 2;
    float*          mkf  = (float*)ws;          ws += (size_t)BB * SENC * 4;

    prep_kernel<<<4097, 256, 0, stream>>>(dec, enc, decb, encb, q_w, k_w, v_w, o_w,
                                          qwt, kvwt, owt, emask, mkf);
    gemm_qkv_kernel<<<1280, 256, 0, stream>>>(encb, decb, kvwt, qwt, q_b, k_b, v_b, Qb, Kb, Vtb);
    attn_kernel<<<1024, 256, 0, stream>>>(Qb, Kb, Vtb, mkf, Xb);
    gemm_o_kernel<<<512, 256, 0, stream>>>(Xb, owt, o_b, out);
}